// Round 4
// baseline (470.844 us; speedup 1.0000x reference)
//
#include <hip/hip_runtime.h>
#include <hip/hip_bf16.h>

#define K_IN 2624     // 2048 + 512 + 64
#define NSTEP 82      // K-steps of 32 (prep granularity)
#define NCH 82        // lstm: BK=32 chunks

typedef __attribute__((ext_vector_type(8))) short short8;
typedef __attribute__((ext_vector_type(4))) short short4_t;
typedef __attribute__((ext_vector_type(4))) float float4_t;

__device__ __forceinline__ short f2bf(float f) {
    union { __hip_bfloat16 b; short s; } u;
    u.b = __float2bfloat16(f);
    return u.s;
}

__device__ __forceinline__ float sigmoid_fast(float x) {
    return 1.f / (1.f + __expf(-x));
}

__device__ __forceinline__ float tanh_fast(float x) {
    float e = __expf(-2.f * fabsf(x));
    float t = (1.f - e) / (1.f + e);
    return copysignf(t, x);
}

// ---------------------------------------------------------------------------
// prep: pack fused weight [Wi;Wh] (K_IN x 256, fp32, k-major) into
// MFMA-B-fragment order, bf16:
//   Wt2[kstep s][nb][lane][8elem]: lane l holds B[k=s*32+(l>>4)*8+j][n=nb*16+(l&15)].
// Also bsum[n] = bi[n]+bh[n].
// ---------------------------------------------------------------------------
__global__ void prep_kernel(const float* __restrict__ Wi, const float* __restrict__ bi,
                            const float* __restrict__ Wh, const float* __restrict__ bh,
                            short* __restrict__ Wt2, float* __restrict__ bsum) {
    __shared__ short tile[32][264];   // +8 pad
    const int t = threadIdx.x;
    const int kb = blockIdx.x;
    const int k0 = kb * 32;

#pragma unroll 8
    for (int j = 0; j < 32; ++j) {
        int k = k0 + j;
        float v = (k < 2560) ? Wi[(size_t)k * 256 + t]
                             : Wh[(size_t)(k - 2560) * 256 + t];
        tile[j][t] = f2bf(v);
    }
    if (kb == 0) bsum[t] = bi[t] + bh[t];
    __syncthreads();

#pragma unroll
    for (int c = 0; c < 4; ++c) {
        int idx = c * 256 + t;          // 0..1023 = nb*64 + lane
        int lane = idx & 63;
        int nb = idx >> 6;
        int n = nb * 16 + (lane & 15);
        int j0 = (lane >> 4) * 8;
        short8 v;
#pragma unroll
        for (int j = 0; j < 8; ++j) v[j] = tile[j0 + j][n];
        *reinterpret_cast<short8*>(Wt2 + (size_t)kb * 8192 + (size_t)idx * 8) = v;
    }
}

// ---------------------------------------------------------------------------
// Fused GEMM + LSTM, round 4: occupancy-first.
// 1024 blocks x 256 threads (4 waves) = 4 blocks/CU, 16 waves/CU.
// Block owns 32 batch rows x all 256 gate cols; wave w owns those 32 rows x
// n-cols [w*64, w*64+64) -> acc = 2x4 frags = 32 VGPRs.
// A: fp32 global->reg (distance-2 prefetch, ages a full body before the
//    barrier drain) -> bf16 -> LDS (shared by all 4 waves).
// B: global_load_lds width-16 into a BK=32 double buffer.
// LDS 36 KB/block; one __syncthreads per chunk.
// ---------------------------------------------------------------------------
__global__ __launch_bounds__(256, 4)
void lstm_kernel(const float* __restrict__ state, const float* __restrict__ action,
                 const float* __restrict__ hidden, const float* __restrict__ cell,
                 const short* __restrict__ Wt2, const float* __restrict__ bsum,
                 const float* __restrict__ Wo, const float* __restrict__ bo,
                 float* __restrict__ out, int Brows) {
    __shared__ __align__(16) char smem[36864];
    short* sB = (short*)smem;               // 2 x [16 nb][512] = 2 x 16 KB
    short* sA = (short*)(smem + 32768);     // 2 x [32 rows][32 k] = 2 x 2 KB
    float* sG = (float*)smem;               // epilogue overlay: [32][260] fp32

    const int t = threadIdx.x;
    const int w = t >> 6;
    const int l = t & 63;
    const int lr = l & 15;
    const int q = l >> 4;
    const int bm = blockIdx.x;

    // A staging coords: thread -> (row ar, k-offset akc) of the 32x32 tile
    const int ar = t >> 3;          // 0..31
    const int akc = (t & 7) * 4;    // 0,4,..,28

    const size_t rowbase = (size_t)bm * 32;
    const float* aS = state  + (rowbase + ar) * 2048 + akc;
    const float* aA = action + (rowbase + ar) * 512  + akc;
    const float* aH = hidden + (rowbase + ar) * 64   + akc;

    float4_t acc[2][4];
#pragma unroll
    for (int mt = 0; mt < 2; ++mt)
#pragma unroll
        for (int nt = 0; nt < 4; ++nt) acc[mt][nt] = (float4_t)(0.f);

    auto loadA = [&](int c) -> float4_t {
        const float* p;
        if (c < 64)      p = aS + c * 32;
        else if (c < 80) p = aA + (c - 64) * 32;
        else             p = aH + (c - 80) * 32;
        return __builtin_nontemporal_load(reinterpret_cast<const float4_t*>(p));
    };
    auto writeA = [&](int slot, float4_t v) {
        short4_t s4;
        s4[0] = f2bf(v[0]); s4[1] = f2bf(v[1]); s4[2] = f2bf(v[2]); s4[3] = f2bf(v[3]);
        *reinterpret_cast<short4_t*>(sA + slot * 1024 + ar * 32 + akc) = s4;
    };
    auto stageB = [&](int c) {
        const int slot = c & 1;
#pragma unroll
        for (int i = 0; i < 4; ++i) {
            int blk = w * 4 + i;    // 1KB chunk 0..15
            __builtin_amdgcn_global_load_lds(
                (const __attribute__((address_space(1))) void*)(Wt2 + (size_t)c * 8192 + blk * 512 + l * 8),
                (__attribute__((address_space(3))) void*)(sB + slot * 8192 + blk * 512),
                16, 0, 0);
        }
    };

    float4_t aG[2];

    // prologue
    stageB(0);
    aG[0] = loadA(0);
    aG[1] = loadA(1);
    writeA(0, aG[0]);
    __syncthreads();

#pragma unroll 2
    for (int k = 0; k < NCH; ++k) {
        const int slot = k & 1;
        if (k + 1 < NCH) stageB(k + 1);
        if (k + 2 < NCH) aG[k & 1] = loadA(k + 2);

        // compute chunk k
        short8 a0 = *reinterpret_cast<const short8*>(sA + slot * 1024 + lr * 32 + q * 8);
        short8 a1 = *reinterpret_cast<const short8*>(sA + slot * 1024 + (16 + lr) * 32 + q * 8);
        short8 b[4];
#pragma unroll
        for (int nt = 0; nt < 4; ++nt)
            b[nt] = *reinterpret_cast<const short8*>(sB + slot * 8192 + (w * 4 + nt) * 512 + l * 8);
#pragma unroll
        for (int nt = 0; nt < 4; ++nt)
            acc[0][nt] = __builtin_amdgcn_mfma_f32_16x16x32_bf16(a0, b[nt], acc[0][nt], 0, 0, 0);
#pragma unroll
        for (int nt = 0; nt < 4; ++nt)
            acc[1][nt] = __builtin_amdgcn_mfma_f32_16x16x32_bf16(a1, b[nt], acc[1][nt], 0, 0, 0);

        if (k + 1 < NCH) writeA((k + 1) & 1, aG[(k + 1) & 1]);
        __syncthreads();
    }

    // ---- epilogue: gates -> LDS -> LSTM -> h@Wo ----
    // C-layout: row = mt*16 + q*4 + r, col = w*64 + nt*16 + lr
#pragma unroll
    for (int mt = 0; mt < 2; ++mt)
#pragma unroll
        for (int nt = 0; nt < 4; ++nt)
#pragma unroll
            for (int r = 0; r < 4; ++r)
                sG[(mt * 16 + q * 4 + r) * 260 + w * 64 + nt * 16 + lr] = acc[mt][nt][r];
    __syncthreads();

    const float wo = Wo[l];
    const float bov = bo[0];
    const float b0 = bsum[l];
    const float b1 = bsum[64 + l];
    const float b2 = bsum[128 + l];
    const float b3 = bsum[192 + l];
    float* outH = out + Brows;
    float* outC = outH + (size_t)Brows * 64;

#pragma unroll
    for (int r = 0; r < 8; ++r) {
        int rr = w * 8 + r;
        size_t grow = rowbase + rr;
        float gi = sG[rr * 260 + l]       + b0;
        float gf = sG[rr * 260 + 64 + l]  + b1;
        float gg = sG[rr * 260 + 128 + l] + b2;
        float go = sG[rr * 260 + 192 + l] + b3;
        float i_t = sigmoid_fast(gi);
        float f_t = sigmoid_fast(gf);
        float g_t = tanh_fast(gg);
        float o_t = sigmoid_fast(go);
        float c_t = f_t * cell[grow * 64 + l] + i_t * g_t;
        float h_t = o_t * tanh_fast(c_t);
        outC[grow * 64 + l] = c_t;
        outH[grow * 64 + l] = h_t;
        float v = h_t * wo;
#pragma unroll
        for (int off = 32; off > 0; off >>= 1) v += __shfl_down(v, off);
        if (l == 0) out[grow] = tanh_fast(v + bov);
    }
}

extern "C" void kernel_launch(void* const* d_in, const int* in_sizes, int n_in,
                              void* d_out, int out_size, void* d_ws, size_t ws_size,
                              hipStream_t stream) {
    const float* state  = (const float*)d_in[0];
    const float* action = (const float*)d_in[1];
    const float* hidden = (const float*)d_in[2];
    const float* cell   = (const float*)d_in[3];
    const float* Wi     = (const float*)d_in[4];
    const float* bi     = (const float*)d_in[5];
    const float* Wh     = (const float*)d_in[6];
    const float* bh     = (const float*)d_in[7];
    const float* Wo     = (const float*)d_in[8];
    const float* bo     = (const float*)d_in[9];

    const int Brows = in_sizes[0] / 2048;   // 32768

    short* Wt2  = (short*)d_ws;                                    // 82*8192 bf16
    float* bsum = (float*)((char*)d_ws + (size_t)NSTEP * 8192 * sizeof(short));

    prep_kernel<<<NSTEP, 256, 0, stream>>>(Wi, bi, Wh, bh, Wt2, bsum);
    lstm_kernel<<<Brows / 32, 256, 0, stream>>>(state, action, hidden, cell,
                                                Wt2, bsum, Wo, bo, (float*)d_out, Brows);
}